// Round 10
// baseline (487.920 us; speedup 1.0000x reference)
//
#include <hip/hip_runtime.h>

#define B_ 4096
#define T_ 512
#define F_ 8
#define H_ 16

typedef float f32x4v __attribute__((ext_vector_type(4)));

#define LOG2E 1.442695041f
#define N2LOG2E (-2.885390082f)

__device__ __forceinline__ float sigf(float x) {
    return __builtin_amdgcn_rcpf(1.0f + __builtin_amdgcn_exp2f(-LOG2E * x));
}
__device__ __forceinline__ float tanh_f(float x) {
    return __builtin_fmaf(2.0f,
        __builtin_amdgcn_rcpf(1.0f + __builtin_amdgcn_exp2f(N2LOG2E * x)), -1.0f);
}

// DPP row_ror:K: dst[i] = src[(i-K)&15] within each 16-lane row (full masks)
template <int K>
__device__ __forceinline__ float rotr(float v) {
    int i = __builtin_bit_cast(int, v);
    return __builtin_bit_cast(float,
        __builtin_amdgcn_update_dpp(i, i, 0x120 + K, 0xF, 0xF, false));
}
// row_ror:8 applied ONLY to rows 2,3 (lanes 32-63); rows 0,1 keep old value.
__device__ __forceinline__ float ror8_hi(float v) {
    int i = __builtin_bit_cast(int, v);
    return __builtin_bit_cast(float,
        __builtin_amdgcn_update_dpp(i, i, 0x128, 0xC, 0xF, false));
}

// 2 chains/wave, K-split lanes -> 2048 waves = 2 waves/SIMD (hides the serial
// chain that capped R6 at 53% busy). Lane l: chain ch=(l>>4)&1, K-half
// kh=l>>5, unit u=l&15. Lane computes all 4 gate rows of unit u over its
// 8-unit h-half + 4 x-features (48 MACs = half of R6's per-lane matvec).
// h-share is pure DPP: h8 = row-masked ror:8 (kh=1 rows only), then
// hj[j] = rotr<j>(h8) = h_{(u-j-8kh)&15}; weights pre-gathered in the same
// sliding-window pattern so the two halves tile k=0..15. Half-partials
// combine with one shfl_xor(32) per gate (partner = lane^32 = same (ch,u),
// other kh). Both halves then compute identical cell/ht (same full sums).
// No LDS in the recurrent path; x staging only. Bias/xp seeded in kh=0 only.
__global__ __launch_bounds__(256, 2) void lstm_ae_kernel(
    const float* __restrict__ x,
    const float* __restrict__ eWih, const float* __restrict__ eWhh,
    const float* __restrict__ ebih, const float* __restrict__ ebhh,
    const float* __restrict__ dWih, const float* __restrict__ dWhh,
    const float* __restrict__ dbih, const float* __restrict__ dbhh,
    const float* __restrict__ oW,   const float* __restrict__ ob,
    float* __restrict__ out)
{
    const int tid = threadIdx.x;
    const int wv  = tid >> 6;          // wave in block, 0..3
    const int l   = tid & 63;
    const int ch  = (l >> 4) & 1;      // chain within wave
    const int kh  = l >> 5;            // K-half: h[8kh..8kh+7], x[4kh..4kh+3]
    const int u   = l & 15;            // hidden unit
    const int b0  = blockIdx.x * 8 + wv * 2;
    const int b   = b0 + ch;

    __shared__ __align__(16) float xsh[4][2][33][8];

    // ---------------- encoder weights (sliding-window gather) --------------
    float wr[4][8], wi4[4][4], bias0[4];
#pragma unroll
    for (int g = 0; g < 4; ++g) {
        const int r = g * 16 + u;
#pragma unroll
        for (int j = 0; j < 8; ++j)
            wr[g][j] = eWhh[r * 16 + ((u - j - 8 * kh) & 15)];
#pragma unroll
        for (int j = 0; j < 4; ++j)
            wi4[g][j] = eWih[r * 8 + kh * 4 + j];
        bias0[g] = (kh == 0) ? (ebih[r] + ebhh[r]) : 0.0f;
    }

    float c = 0.0f;
    float hj[8];
#pragma unroll
    for (int j = 0; j < 8; ++j) hj[j] = 0.0f;

    // x staging: lane covers step sA=l>>1, half hA=(l&1)*4, both chains
    const int sA = l >> 1, hA = (l & 1) * 4;
    const float* xb0 = x + (size_t)b0 * (T_ * F_);
    const float* xb1 = x + (size_t)(b0 + 1) * (T_ * F_);
    f32x4v xr0 = *(const f32x4v*)(xb0 + sA * F_ + hA);
    f32x4v xr1 = *(const f32x4v*)(xb1 + sA * F_ + hA);

    // ---------------- encoder ----------------
    for (int c0 = 0; c0 < T_; c0 += 32) {
        __builtin_amdgcn_wave_barrier();
        *(f32x4v*)&xsh[wv][0][sA][hA] = xr0;
        *(f32x4v*)&xsh[wv][1][sA][hA] = xr1;
        __builtin_amdgcn_wave_barrier();
        if (c0 + 32 < T_) {
            xr0 = *(const f32x4v*)(xb0 + (c0 + 32 + sA) * F_ + hA);
            xr1 = *(const f32x4v*)(xb1 + (c0 + 32 + sA) * F_ + hA);
        }
        // 1-step read-ahead keeps ds_read latency off the serial path
        f32x4v xv = *(const f32x4v*)&xsh[wv][ch][0][kh * 4];
        for (int s = 0; s < 32; ++s) {
            f32x4v nx = *(const f32x4v*)&xsh[wv][ch][s + 1][kh * 4]; // row 32 pad
            float sg[4];
#pragma unroll
            for (int g = 0; g < 4; ++g) {
                float a = bias0[g];
                a = __builtin_fmaf(wi4[g][0], xv[0], a);
                a = __builtin_fmaf(wi4[g][1], xv[1], a);
                a = __builtin_fmaf(wi4[g][2], xv[2], a);
                a = __builtin_fmaf(wi4[g][3], xv[3], a);
#pragma unroll
                for (int j = 0; j < 8; ++j)
                    a = __builtin_fmaf(wr[g][j], hj[j], a);
                sg[g] = a;
            }
            // combine K-halves (partner = lane^32)
            sg[0] += __shfl_xor(sg[0], 32, 64);
            sg[1] += __shfl_xor(sg[1], 32, 64);
            sg[2] += __shfl_xor(sg[2], 32, 64);
            sg[3] += __shfl_xor(sg[3], 32, 64);

            const float gi = sigf(sg[0]);
            const float gf = sigf(sg[1]);
            const float gg = tanh_f(sg[2]);
            const float go = sigf(sg[3]);
            c = __builtin_fmaf(gf, c, gi * gg);
            const float ht = go * tanh_f(c);

            const float h8 = ror8_hi(ht);      // kh=1 rows pre-rotated by 8
            hj[0] = h8;
            hj[1] = rotr<1>(h8); hj[2] = rotr<2>(h8); hj[3] = rotr<3>(h8);
            hj[4] = rotr<4>(h8); hj[5] = rotr<5>(h8); hj[6] = rotr<6>(h8);
            hj[7] = rotr<7>(h8);
            xv = nx;
        }
    }

    // ---------- decoder weights + PARTIAL constant x-projection -----------
    // xpp stays a half-partial; the per-step gate combine sums both halves.
    float wd[4][8], wo[8], xpp[4];
#pragma unroll
    for (int g = 0; g < 4; ++g) {
        const int r = g * 16 + u;
        float a = (kh == 0) ? (dbih[r] + dbhh[r]) : 0.0f;
#pragma unroll
        for (int j = 0; j < 8; ++j) {
            const int idx = (u - j - 8 * kh) & 15;
            a = __builtin_fmaf(dWih[r * 16 + idx], hj[j], a);
            wd[g][j] = dWhh[r * 16 + idx];
        }
        xpp[g] = a;
    }
    const int fo = u & 7;
#pragma unroll
    for (int j = 0; j < 8; ++j)
        wo[j] = oW[fo * 16 + ((u - j - 8 * kh) & 15)];
    const float obv = ob[fo];
    const bool st = (u < 8) && (kh == 0);
    float* outp = out + (size_t)b * (T_ * F_);

    c = 0.0f;
#pragma unroll
    for (int j = 0; j < 8; ++j) hj[j] = 0.0f;

    // ---------------- decoder + fused output projection ----------------
#pragma unroll 2
    for (int t = 0; t < T_; ++t) {
        float sg[4];
#pragma unroll
        for (int g = 0; g < 4; ++g) {
            float a = xpp[g];
#pragma unroll
            for (int j = 0; j < 8; ++j)
                a = __builtin_fmaf(wd[g][j], hj[j], a);
            sg[g] = a;
        }
        sg[0] += __shfl_xor(sg[0], 32, 64);
        sg[1] += __shfl_xor(sg[1], 32, 64);
        sg[2] += __shfl_xor(sg[2], 32, 64);
        sg[3] += __shfl_xor(sg[3], 32, 64);

        const float gi = sigf(sg[0]);
        const float gf = sigf(sg[1]);
        const float gg = tanh_f(sg[2]);
        const float go = sigf(sg[3]);
        c = __builtin_fmaf(gf, c, gi * gg);
        const float ht = go * tanh_f(c);

        const float h8 = ror8_hi(ht);
        hj[0] = h8;
        hj[1] = rotr<1>(h8); hj[2] = rotr<2>(h8); hj[3] = rotr<3>(h8);
        hj[4] = rotr<4>(h8); hj[5] = rotr<5>(h8); hj[6] = rotr<6>(h8);
        hj[7] = rotr<7>(h8);

        // fused output projection (feature u&7), half-K partial + combine
        float oa = 0.0f;
#pragma unroll
        for (int j = 0; j < 8; ++j)
            oa = __builtin_fmaf(wo[j], hj[j], oa);
        oa += __shfl_xor(oa, 32, 64);
        if (st) outp[t * F_ + u] = oa + obv;
    }
}

extern "C" void kernel_launch(void* const* d_in, const int* in_sizes, int n_in,
                              void* d_out, int out_size, void* d_ws, size_t ws_size,
                              hipStream_t stream) {
    (void)in_sizes; (void)n_in; (void)d_ws; (void)ws_size; (void)out_size;
    lstm_ae_kernel<<<dim3(B_ / 8), dim3(256), 0, stream>>>(
        (const float*)d_in[0],
        (const float*)d_in[1], (const float*)d_in[2],
        (const float*)d_in[3], (const float*)d_in[4],
        (const float*)d_in[5], (const float*)d_in[6],
        (const float*)d_in[7], (const float*)d_in[8],
        (const float*)d_in[9], (const float*)d_in[10],
        (float*)d_out);
}

// Round 11
// 364.083 us; speedup vs baseline: 1.3401x; 1.3401x over previous
//
#include <hip/hip_runtime.h>

#define B_ 4096
#define T_ 512
#define F_ 8
#define H_ 16

typedef float f32x2 __attribute__((ext_vector_type(2)));
typedef float f32x4v __attribute__((ext_vector_type(4)));

__device__ __forceinline__ f32x2 pkfma(f32x2 a, f32x2 b, f32x2 c) {
    return __builtin_elementwise_fma(a, b, c);
}
#define SV2(v, a, b) __builtin_shufflevector(v, v, a, b)

#define LOG2E 1.442695041f
#define N2LOG2E (-2.885390082f)

__device__ __forceinline__ float sigf(float x) {
    return __builtin_amdgcn_rcpf(1.0f + __builtin_amdgcn_exp2f(-LOG2E * x));
}
__device__ __forceinline__ float tanh_f(float x) {
    return __builtin_fmaf(2.0f,
        __builtin_amdgcn_rcpf(1.0f + __builtin_amdgcn_exp2f(N2LOG2E * x)), -1.0f);
}

// R6 structure (295us, best measured): 4 chains/wave, gate-quad locality.
// Lane l: chain cw=l>>4, unit u=l&15, owns gate rows {u,u+16,u+32,u+48} ->
// every activation computed exactly once, zero cross-lane gate exchange.
// h broadcast via LDS write + 4x b128 broadcast read.
// R11 change: FILL THE LDS ROUNDTRIP WINDOW (R6's 47% stall = write->read
// latency with zero instructions between). Encoder: x-projection of step s+1
// (16 pk + 2 ds_read, h-independent) computed between h-write(s) and
// h-read(s). Decoder: output projection skewed one step - out[t-1] computed
// from the register copy of h(t-1) inside step t's window; epilogue emits
// out[T-1]. Pure reschedule of R6's instruction set; no new exchanges.
__global__ __launch_bounds__(256, 1) void lstm_ae_kernel(
    const float* __restrict__ x,
    const float* __restrict__ eWih, const float* __restrict__ eWhh,
    const float* __restrict__ ebih, const float* __restrict__ ebhh,
    const float* __restrict__ dWih, const float* __restrict__ dWhh,
    const float* __restrict__ dbih, const float* __restrict__ dbhh,
    const float* __restrict__ oW,   const float* __restrict__ ob,
    float* __restrict__ out)
{
    const int tid = threadIdx.x;
    const int wv  = tid >> 6;        // wave in block
    const int l   = tid & 63;
    const int cw  = l >> 4;          // chain within wave, 0..3
    const int u   = l & 15;          // hidden unit (lane within 16-row)
    const int bw  = blockIdx.x * 16 + wv * 4;
    const int b   = bw + cw;

    // padded strides (R6): h group stride 10 f32x2; x chain stride 33 steps
    __shared__ __align__(16) f32x2 hsh[4][40];
    __shared__ __align__(16) f32x2 xsh[4][4][33][4];

    const f32x2 zero2 = {0.0f, 0.0f};

    // ---------------- encoder weights ----------------
    f32x2 wh[4][8], wi[4][4], bias2[4];
#pragma unroll
    for (int g = 0; g < 4; ++g) {
        const int r = g * 16 + u;
        const f32x2* phh = (const f32x2*)(eWhh + r * 16);
#pragma unroll
        for (int p = 0; p < 8; ++p) wh[g][p] = phh[p];
        const f32x2* pih = (const f32x2*)(eWih + r * 8);
#pragma unroll
        for (int p = 0; p < 4; ++p) wi[g][p] = pih[p];
        bias2[g] = f32x2{ebih[r] + ebhh[r], 0.0f};
    }

    float c = 0.0f;
    f32x2 hb[8];
#pragma unroll
    for (int p = 0; p < 8; ++p) hb[p] = zero2;

    float* hp = (float*)&hsh[wv][cw * 10];

    // x chunk prefetch: iter i covers chain bw+i, step c0+(l>>1), half l&1
    const int ps = l >> 1, phx = l & 1;
    f32x4v xr[4];
#pragma unroll
    for (int i = 0; i < 4; ++i)
        xr[i] = *(const f32x4v*)(x + ((size_t)(bw + i) * T_ + ps) * F_ + phx * 4);

    // xacc: x-projection of the CURRENT step (pipelined one step ahead)
    f32x2 xaA[4], xaB[4];

    // ---------------- encoder ----------------
    for (int c0 = 0; c0 < T_; c0 += 32) {
        __builtin_amdgcn_wave_barrier();
#pragma unroll
        for (int i = 0; i < 4; ++i)
            *(f32x4v*)&xsh[wv][i][ps][phx * 2] = xr[i];
        __builtin_amdgcn_wave_barrier();
        if (c0 + 32 < T_) {
#pragma unroll
            for (int i = 0; i < 4; ++i)
                xr[i] = *(const f32x4v*)(
                    x + ((size_t)(bw + i) * T_ + (c0 + 32 + ps)) * F_ + phx * 4);
        }
        // x-projection for row 0 of this chunk
        {
            f32x4v q0 = *(const f32x4v*)&xsh[wv][cw][0][0];
            f32x4v q1 = *(const f32x4v*)&xsh[wv][cw][0][2];
            f32x2 x0 = SV2(q0, 0, 1), x1 = SV2(q0, 2, 3);
            f32x2 x2 = SV2(q1, 0, 1), x3 = SV2(q1, 2, 3);
#pragma unroll
            for (int g = 0; g < 4; ++g) {
                f32x2 a = pkfma(wi[g][0], x0, bias2[g]);
                f32x2 bq = pkfma(wi[g][1], x1, zero2);
                xaA[g] = pkfma(wi[g][2], x2, a);
                xaB[g] = pkfma(wi[g][3], x3, bq);
            }
        }
        for (int s = 0; s < 32; ++s) {
            float sg[4];
#pragma unroll
            for (int g = 0; g < 4; ++g) {
                f32x2 aa = xaA[g], ab = xaB[g];
#pragma unroll
                for (int p = 0; p < 8; p += 2) {
                    aa = pkfma(wh[g][p],   hb[p],   aa);
                    ab = pkfma(wh[g][p+1], hb[p+1], ab);
                }
                f32x2 ts = aa + ab;
                sg[g] = ts.x + ts.y;
            }
            const float gi = sigf(sg[0]);
            const float gf = sigf(sg[1]);
            const float gg = tanh_f(sg[2]);
            const float go = sigf(sg[3]);
            c = __builtin_fmaf(gf, c, gi * gg);
            const float ht = go * tanh_f(c);

            __builtin_amdgcn_wave_barrier();
            hp[u] = ht;
            __builtin_amdgcn_wave_barrier();
            // WINDOW: x-projection of step s+1 (row 32 = pad, recomputed at
            // next chunk top) fills the LDS write->read latency
            {
                f32x4v q0 = *(const f32x4v*)&xsh[wv][cw][s + 1][0];
                f32x4v q1 = *(const f32x4v*)&xsh[wv][cw][s + 1][2];
                f32x2 x0 = SV2(q0, 0, 1), x1 = SV2(q0, 2, 3);
                f32x2 x2 = SV2(q1, 0, 1), x3 = SV2(q1, 2, 3);
#pragma unroll
                for (int g = 0; g < 4; ++g) {
                    f32x2 a = pkfma(wi[g][0], x0, bias2[g]);
                    f32x2 bq = pkfma(wi[g][1], x1, zero2);
                    xaA[g] = pkfma(wi[g][2], x2, a);
                    xaB[g] = pkfma(wi[g][3], x3, bq);
                }
            }
            __builtin_amdgcn_wave_barrier();
            f32x4v h0 = *(const f32x4v*)&hp[0];
            f32x4v h1 = *(const f32x4v*)&hp[4];
            f32x4v h2 = *(const f32x4v*)&hp[8];
            f32x4v h3 = *(const f32x4v*)&hp[12];
            hb[0] = SV2(h0, 0, 1); hb[1] = SV2(h0, 2, 3);
            hb[2] = SV2(h1, 0, 1); hb[3] = SV2(h1, 2, 3);
            hb[4] = SV2(h2, 0, 1); hb[5] = SV2(h2, 2, 3);
            hb[6] = SV2(h3, 0, 1); hb[7] = SV2(h3, 2, 3);
        }
    }

    // ---------- decoder weights + constant input projection ----------
    f32x2 wd[4][8], xp2[4];
#pragma unroll
    for (int g = 0; g < 4; ++g) {
        const int r = g * 16 + u;
        const f32x2* pih = (const f32x2*)(dWih + r * 16);
        f32x2 a = zero2;
#pragma unroll
        for (int p = 0; p < 8; ++p) a = pkfma(pih[p], hb[p], a);
        xp2[g] = f32x2{dbih[r] + dbhh[r] + a.x + a.y, 0.0f};
        const f32x2* phh = (const f32x2*)(dWhh + r * 16);
#pragma unroll
        for (int p = 0; p < 8; ++p) wd[g][p] = phh[p];
    }
    f32x2 wo[8];
    {
        const f32x2* po = (const f32x2*)(oW + (u & 7) * 16);
#pragma unroll
        for (int p = 0; p < 8; ++p) wo[p] = po[p];
    }
    const f32x2 ob2 = {ob[u & 7], 0.0f};
    const bool st = (u < 8);
    float* outp = out + (size_t)b * (T_ * F_);

    c = 0.0f;
#pragma unroll
    for (int p = 0; p < 8; ++p) hb[p] = zero2;

    // ---------------- decoder, oproj skewed by one step ----------------
    for (int t = 0; t < T_; ++t) {
        float sg[4];
#pragma unroll
        for (int g = 0; g < 4; ++g) {
            f32x2 aa = pkfma(wd[g][0], hb[0], xp2[g]);
            f32x2 ab = pkfma(wd[g][1], hb[1], zero2);
#pragma unroll
            for (int p = 2; p < 8; p += 2) {
                aa = pkfma(wd[g][p],   hb[p],   aa);
                ab = pkfma(wd[g][p+1], hb[p+1], ab);
            }
            f32x2 ts = aa + ab;
            sg[g] = ts.x + ts.y;
        }
        const float gi = sigf(sg[0]);
        const float gf = sigf(sg[1]);
        const float gg = tanh_f(sg[2]);
        const float go = sigf(sg[3]);
        c = __builtin_fmaf(gf, c, gi * gg);
        const float ht = go * tanh_f(c);

        __builtin_amdgcn_wave_barrier();
        hp[u] = ht;
        __builtin_amdgcn_wave_barrier();
        // WINDOW: out[t-1] from the register copy of h(t-1) fills the LDS
        // write->read latency (t=0: hb=0, not stored)
        {
            f32x2 oa  = pkfma(wo[0], hb[0], ob2);
            f32x2 obb = pkfma(wo[1], hb[1], zero2);
#pragma unroll
            for (int p = 2; p < 8; p += 2) {
                oa  = pkfma(wo[p],   hb[p],   oa);
                obb = pkfma(wo[p+1], hb[p+1], obb);
            }
            f32x2 to = oa + obb;
            if (st && t > 0) outp[(t - 1) * F_ + u] = to.x + to.y;
        }
        __builtin_amdgcn_wave_barrier();
        f32x4v h0 = *(const f32x4v*)&hp[0];
        f32x4v h1 = *(const f32x4v*)&hp[4];
        f32x4v h2 = *(const f32x4v*)&hp[8];
        f32x4v h3 = *(const f32x4v*)&hp[12];
        hb[0] = SV2(h0, 0, 1); hb[1] = SV2(h0, 2, 3);
        hb[2] = SV2(h1, 0, 1); hb[3] = SV2(h1, 2, 3);
        hb[4] = SV2(h2, 0, 1); hb[5] = SV2(h2, 2, 3);
        hb[6] = SV2(h3, 0, 1); hb[7] = SV2(h3, 2, 3);
    }
    // epilogue: out[T-1] from h(T-1)
    {
        f32x2 oa  = pkfma(wo[0], hb[0], ob2);
        f32x2 obb = pkfma(wo[1], hb[1], zero2);
#pragma unroll
        for (int p = 2; p < 8; p += 2) {
            oa  = pkfma(wo[p],   hb[p],   oa);
            obb = pkfma(wo[p+1], hb[p+1], obb);
        }
        f32x2 to = oa + obb;
        if (st) outp[(T_ - 1) * F_ + u] = to.x + to.y;
    }
}

extern "C" void kernel_launch(void* const* d_in, const int* in_sizes, int n_in,
                              void* d_out, int out_size, void* d_ws, size_t ws_size,
                              hipStream_t stream) {
    (void)in_sizes; (void)n_in; (void)d_ws; (void)ws_size; (void)out_size;
    lstm_ae_kernel<<<dim3(B_ / 16), dim3(256), 0, stream>>>(
        (const float*)d_in[0],
        (const float*)d_in[1], (const float*)d_in[2],
        (const float*)d_in[3], (const float*)d_in[4],
        (const float*)d_in[5], (const float*)d_in[6],
        (const float*)d_in[7], (const float*)d_in[8],
        (const float*)d_in[9], (const float*)d_in[10],
        (float*)d_out);
}

// Round 12
// 354.649 us; speedup vs baseline: 1.3758x; 1.0266x over previous
//
#include <hip/hip_runtime.h>

#define B_ 4096
#define T_ 512
#define F_ 8
#define H_ 16

typedef float f32x2 __attribute__((ext_vector_type(2)));
typedef float f32x4v __attribute__((ext_vector_type(4)));

__device__ __forceinline__ f32x2 pkfma(f32x2 a, f32x2 b, f32x2 c) {
    return __builtin_elementwise_fma(a, b, c);
}

#define L2E 1.442695041f
#define N2L2E (-2.885390082f)
#define WB() __builtin_amdgcn_wave_barrier()

// R6 structure (295us best): 4 chains/wave, gate-quad locality. Lane l:
// chain cw=l>>4, unit u=l&15, owns gate rows {u,u+16,u+32,u+48}; every
// activation computed once; h broadcast via LDS.
// R12 changes (why R11's window-fill was a no-op):
//  1) Pipeline ORDER fixed: h-write -> h-reads ISSUE IMMEDIATELY (b64 x8 into
//     the non-live buffer of an unroll-2 double buffer) -> REGISTER-ONLY
//     filler (enc: xproj(s+1) from x read at step top; dec: oproj(t-1) from
//     the live buffer) -> wait. R11 had the reads behind the filler (dec) and
//     LDS-dependent filler (enc), so the 120cy read flight started late.
//  2) All h/x LDS reads as f32x2 (ds_read_b64): kills 16 unpack movs/step.
//  3) Fused gates: i*g=(1-u)*rcp((1+pi)(1+u)), o*tanh(c)=(1-v)*rcp((1+po)(1+v))
//     -> 5 exp + 3 rcp (was 10 trans); clamps stop exp2 overflow -> NaN.
__global__ __launch_bounds__(256, 1) void lstm_ae_kernel(
    const float* __restrict__ x,
    const float* __restrict__ eWih, const float* __restrict__ eWhh,
    const float* __restrict__ ebih, const float* __restrict__ ebhh,
    const float* __restrict__ dWih, const float* __restrict__ dWhh,
    const float* __restrict__ dbih, const float* __restrict__ dbhh,
    const float* __restrict__ oW,   const float* __restrict__ ob,
    float* __restrict__ out)
{
    const int tid = threadIdx.x;
    const int wv  = tid >> 6;        // wave in block
    const int l   = tid & 63;
    const int cw  = l >> 4;          // chain within wave, 0..3
    const int u   = l & 15;          // hidden unit
    const int bw  = blockIdx.x * 16 + wv * 4;
    const int b   = bw + cw;

    // padded strides: h chain stride 10 f32x2 (80B); x chain stride 33 rows
    __shared__ __align__(16) f32x2 hsh[4][40];
    __shared__ __align__(16) f32x2 xsh[4][4][33][4];

    const f32x2 zero2 = {0.0f, 0.0f};

    // ---------------- encoder weights ----------------
    f32x2 wh[4][8], wi[4][4], bias2[4];
#pragma unroll
    for (int g = 0; g < 4; ++g) {
        const int r = g * 16 + u;
        const f32x2* phh = (const f32x2*)(eWhh + r * 16);
#pragma unroll
        for (int p = 0; p < 8; ++p) wh[g][p] = phh[p];
        const f32x2* pih = (const f32x2*)(eWih + r * 8);
#pragma unroll
        for (int p = 0; p < 4; ++p) wi[g][p] = pih[p];
        bias2[g] = f32x2{ebih[r] + ebhh[r], 0.0f};
    }

    float c = 0.0f;
    f32x2 hbA[8], hbB[8];
#pragma unroll
    for (int p = 0; p < 8; ++p) { hbA[p] = zero2; hbB[p] = zero2; }

    float* hp = (float*)&hsh[wv][cw * 10];
    const f32x2* hv2 = (const f32x2*)hp;

    // x chunk prefetch: iter i covers chain bw+i, step c0+(l>>1), half l&1
    const int ps = l >> 1, phx = l & 1;
    f32x4v xr[4];
#pragma unroll
    for (int i = 0; i < 4; ++i)
        xr[i] = *(const f32x4v*)(x + ((size_t)(bw + i) * T_ + ps) * F_ + phx * 4);

    f32x2 xaA[4], xaB[4];            // xproj of the CURRENT step

// gates + cell + ht from sg[4]; writes ht, updates c
#define GATES()                                                           \
    const float pi = __builtin_amdgcn_exp2f(-L2E * sg[0]);                \
    const float pf = __builtin_amdgcn_exp2f(-L2E * sg[1]);                \
    const float ug = __builtin_amdgcn_exp2f(N2L2E * fmaxf(sg[2], -30.f)); \
    const float po = __builtin_amdgcn_exp2f(-L2E * sg[3]);                \
    const float gf = __builtin_amdgcn_rcpf(1.0f + pf);                    \
    const float ig = (1.0f - ug) *                                        \
        __builtin_amdgcn_rcpf((1.0f + pi) * (1.0f + ug));                 \
    c = __builtin_fmaf(gf, c, ig);                                        \
    const float vc = __builtin_amdgcn_exp2f(N2L2E * fmaxf(c, -30.f));     \
    const float ht = (1.0f - vc) *                                        \
        __builtin_amdgcn_rcpf((1.0f + po) * (1.0f + vc));

#define ENC_STEP(HIN, HOUT, S)                                            \
    {                                                                     \
        /* x for step S+1, read at top: 200cy ahead of its (filler) use */ \
        const f32x2* xrow = &xsh[wv][cw][(S) + 1][0];                     \
        f32x2 q0 = xrow[0], q1 = xrow[1], q2 = xrow[2], q3 = xrow[3];     \
        float sg[4];                                                      \
        _Pragma("unroll")                                                 \
        for (int g = 0; g < 4; ++g) {                                     \
            f32x2 aa = xaA[g], ab = xaB[g];                               \
            _Pragma("unroll")                                             \
            for (int p = 0; p < 8; p += 2) {                              \
                aa = pkfma(wh[g][p],   HIN[p],   aa);                     \
                ab = pkfma(wh[g][p+1], HIN[p+1], ab);                     \
            }                                                             \
            f32x2 ts = aa + ab;                                           \
            sg[g] = ts.x + ts.y;                                          \
        }                                                                 \
        GATES();                                                          \
        WB();                                                             \
        hp[u] = ht;                                                       \
        WB();                                                             \
        _Pragma("unroll")                                                 \
        for (int p = 0; p < 8; ++p) HOUT[p] = hv2[p];   /* reads issue */ \
        WB();                                                             \
        /* register-only filler fills the read flight */                  \
        _Pragma("unroll")                                                 \
        for (int g = 0; g < 4; ++g) {                                     \
            f32x2 na = pkfma(wi[g][0], q0, bias2[g]);                     \
            f32x2 nb = pkfma(wi[g][1], q1, zero2);                        \
            xaA[g] = pkfma(wi[g][2], q2, na);                             \
            xaB[g] = pkfma(wi[g][3], q3, nb);                             \
        }                                                                 \
    }

    // ---------------- encoder ----------------
    for (int c0 = 0; c0 < T_; c0 += 32) {
        WB();
#pragma unroll
        for (int i = 0; i < 4; ++i)
            *(f32x4v*)&xsh[wv][i][ps][phx * 2] = xr[i];
        WB();
        if (c0 + 32 < T_) {
#pragma unroll
            for (int i = 0; i < 4; ++i)
                xr[i] = *(const f32x4v*)(
                    x + ((size_t)(bw + i) * T_ + (c0 + 32 + ps)) * F_ + phx * 4);
        }
        // xproj for row 0 of this chunk
        {
            const f32x2* xrow = &xsh[wv][cw][0][0];
            f32x2 x0 = xrow[0], x1 = xrow[1], x2 = xrow[2], x3 = xrow[3];
#pragma unroll
            for (int g = 0; g < 4; ++g) {
                f32x2 na = pkfma(wi[g][0], x0, bias2[g]);
                f32x2 nb = pkfma(wi[g][1], x1, zero2);
                xaA[g] = pkfma(wi[g][2], x2, na);
                xaB[g] = pkfma(wi[g][3], x3, nb);
            }
        }
        for (int s = 0; s < 32; s += 2) {
            ENC_STEP(hbA, hbB, s);       // row 32 x-read = pad, discarded
            ENC_STEP(hbB, hbA, s + 1);
        }
    }
#undef ENC_STEP

    // ---------- decoder weights + constant input projection ----------
    // encoder state ends in hbA (32 steps/chunk, even)
    f32x2 wd[4][8], xp2[4];
#pragma unroll
    for (int g = 0; g < 4; ++g) {
        const int r = g * 16 + u;
        const f32x2* pih = (const f32x2*)(dWih + r * 16);
        f32x2 a = zero2;
#pragma unroll
        for (int p = 0; p < 8; ++p) a = pkfma(pih[p], hbA[p], a);
        xp2[g] = f32x2{dbih[r] + dbhh[r] + a.x + a.y, 0.0f};
        const f32x2* phh = (const f32x2*)(dWhh + r * 16);
#pragma unroll
        for (int p = 0; p < 8; ++p) wd[g][p] = phh[p];
    }
    f32x2 wo[8];
    {
        const f32x2* po2 = (const f32x2*)(oW + (u & 7) * 16);
#pragma unroll
        for (int p = 0; p < 8; ++p) wo[p] = po2[p];
    }
    const f32x2 ob2 = {ob[u & 7], 0.0f};
    const bool st = (u < 8);
    float* outp = out + (size_t)b * (T_ * F_);

    c = 0.0f;
#pragma unroll
    for (int p = 0; p < 8; ++p) { hbA[p] = zero2; hbB[p] = zero2; }

#define DEC_STEP(HIN, HOUT, TT)                                           \
    {                                                                     \
        float sg[4];                                                      \
        _Pragma("unroll")                                                 \
        for (int g = 0; g < 4; ++g) {                                     \
            f32x2 aa = pkfma(wd[g][0], HIN[0], xp2[g]);                   \
            f32x2 ab = pkfma(wd[g][1], HIN[1], zero2);                    \
            _Pragma("unroll")                                             \
            for (int p = 2; p < 8; p += 2) {                              \
                aa = pkfma(wd[g][p],   HIN[p],   aa);                     \
                ab = pkfma(wd[g][p+1], HIN[p+1], ab);                     \
            }                                                             \
            f32x2 ts = aa + ab;                                           \
            sg[g] = ts.x + ts.y;                                          \
        }                                                                 \
        GATES();                                                          \
        WB();                                                             \
        hp[u] = ht;                                                       \
        WB();                                                             \
        _Pragma("unroll")                                                 \
        for (int p = 0; p < 8; ++p) HOUT[p] = hv2[p];   /* reads issue */ \
        WB();                                                             \
        /* register-only filler: out[TT-1] from HIN = h(TT-1) */          \
        f32x2 oa  = pkfma(wo[0], HIN[0], ob2);                            \
        f32x2 obb = pkfma(wo[1], HIN[1], zero2);                          \
        _Pragma("unroll")                                                 \
        for (int p = 2; p < 8; p += 2) {                                  \
            oa  = pkfma(wo[p],   HIN[p],   oa);                           \
            obb = pkfma(wo[p+1], HIN[p+1], obb);                          \
        }                                                                 \
        f32x2 to = oa + obb;                                              \
        if (st && (TT) > 0) outp[((TT) - 1) * F_ + u] = to.x + to.y;      \
    }

    // ---------------- decoder, oproj skewed one step ----------------
    for (int t = 0; t < T_; t += 2) {
        DEC_STEP(hbA, hbB, t);
        DEC_STEP(hbB, hbA, t + 1);
    }
#undef DEC_STEP
    // epilogue: out[T-1] from h(T-1) (in hbA after an even number of steps)
    {
        f32x2 oa  = pkfma(wo[0], hbA[0], ob2);
        f32x2 obb = pkfma(wo[1], hbA[1], zero2);
#pragma unroll
        for (int p = 2; p < 8; p += 2) {
            oa  = pkfma(wo[p],   hbA[p],  oa);
            obb = pkfma(wo[p+1], hbA[p+1], obb);
        }
        f32x2 to = oa + obb;
        if (st) outp[(T_ - 1) * F_ + u] = to.x + to.y;
    }
}

extern "C" void kernel_launch(void* const* d_in, const int* in_sizes, int n_in,
                              void* d_out, int out_size, void* d_ws, size_t ws_size,
                              hipStream_t stream) {
    (void)in_sizes; (void)n_in; (void)d_ws; (void)ws_size; (void)out_size;
    lstm_ae_kernel<<<dim3(B_ / 16), dim3(256), 0, stream>>>(
        (const float*)d_in[0],
        (const float*)d_in[1], (const float*)d_in[2],
        (const float*)d_in[3], (const float*)d_in[4],
        (const float*)d_in[5], (const float*)d_in[6],
        (const float*)d_in[7], (const float*)d_in[8],
        (const float*)d_in[9], (const float*)d_in[10],
        (float*)d_out);
}